// Round 8
// baseline (3066.102 us; speedup 1.0000x reference)
//
#include <hip/hip_runtime.h>
#include <math.h>

#define NB    4096   // batch N
#define FEAT  1024
#define MSUP  512    // SUPPORT
#define G4    4096   // 4*FEAT
#define NWAYS 20     // n_ways fixed to 20 per setup_inputs()

typedef _Float16 f16;
typedef f16 f16x8 __attribute__((ext_vector_type(8)));
typedef f16 f16x4 __attribute__((ext_vector_type(4)));
typedef float f32x4 __attribute__((ext_vector_type(4)));
typedef unsigned int u32;
#define GLOBAL_AS __attribute__((address_space(1)))
#define LDS_AS    __attribute__((address_space(3)))

__device__ __forceinline__ void load_lds16(const void* g, void* l) {
    __builtin_amdgcn_global_load_lds((const GLOBAL_AS u32*)g, (LDS_AS u32*)l, 16, 0, 0);
}

__device__ __forceinline__ float sigm(float x) { return 1.f / (1.f + __expf(-x)); }

// ---------------- f16 MFMA NT GEMM (R2-proven core): C[m,n] = sum_k A[m,k]*B[n,k]
// Up to THREE (A,B,K) pairs accumulated into one C tile (null A terminates).
// 16x16x32 frags, row-major LDS tiles (R3/R4: leave LDS layout alone).
// FUSECELL: gate-interleaved cols (col=4*feat+gate) -> full LSTM cell in epilogue.
// R7 lesson: the recurrence is chaotic (softmax winner-take-all on std-32 logits);
// ANY new per-iteration rounding source ~2e-4 on recurrent state blows up to ~0.27.
// So: c MUST stay f32; cell math must match the R6-passing path exactly.
template<int BM, int BN, int WROWS, int WCOLS, bool OUTF16, bool HASBIAS, bool FUSECELL>
__global__ __launch_bounds__(256) void mfma_nt(
    void* __restrict__ Cv, int ldc,
    const f16* __restrict__ A1, int lda1, const f16* __restrict__ B1, int ldb1, int K1,
    const f16* __restrict__ A2, int lda2, const f16* __restrict__ B2, int ldb2, int K2,
    const f16* __restrict__ A3, int lda3, const f16* __restrict__ B3, int ldb3, int K3,
    const float* __restrict__ bias,
    const f16* __restrict__ pre,     // [NB][G4] permuted cols (FUSECELL)
    const float* __restrict__ fin,   // [NB][FEAT] f32 (FUSECELL)
    float* __restrict__ cbuf,        // block-private c storage, f32 (FUSECELL)
    f16* __restrict__ hh,            // [NB][FEAT] f16 h_next (FUSECELL)
    float* __restrict__ hout,        // [NB][FEAT] f32 d_out (FUSECELL, writeH)
    int first, int writeH)
{
    constexpr int BK = 32;                      // one 16x16x32 MFMA per K-step
    constexpr int WM = BM / WROWS, WN = BN / WCOLS;
    constexpr int FM = WM / 16,   FN = WN / 16;
    __shared__ f16 As[BM][BK];
    __shared__ f16 Bs[BN][BK];
    const int tid  = threadIdx.x;
    const int lane = tid & 63;
    const int wrow = (tid >> 6) % WROWS, wcol = (tid >> 6) / WROWS;
    const int bm = blockIdx.y * BM, bn = blockIdx.x * BN;
    const int lr = lane & 15, lq = lane >> 4;

    f32x4 acc[FM][FN] = {};

    #pragma unroll
    for (int pass = 0; pass < 3; ++pass) {
        const f16* A = pass == 0 ? A1 : (pass == 1 ? A2 : A3);
        const f16* B = pass == 0 ? B1 : (pass == 1 ? B2 : B3);
        const int lda = pass == 0 ? lda1 : (pass == 1 ? lda2 : lda3);
        const int ldb = pass == 0 ? ldb1 : (pass == 1 ? ldb2 : ldb3);
        const int K   = pass == 0 ? K1  : (pass == 1 ? K2  : K3);
        if (!A) break;                          // block-uniform
        #pragma unroll 1
        for (int k0 = 0; k0 < K; k0 += BK) {
            __syncthreads();
            #pragma unroll
            for (int t = 0; t < (BM * 4) / 256; ++t) {
                int c = t * 256 + tid;
                load_lds16(A + (size_t)(bm + (c >> 2)) * lda + k0 + (c & 3) * 8,
                           &As[0][0] + ((size_t)t * 256 + (tid & 192)) * 8);
            }
            #pragma unroll
            for (int t = 0; t < (BN * 4) / 256; ++t) {
                int c = t * 256 + tid;
                load_lds16(B + (size_t)(bn + (c >> 2)) * ldb + k0 + (c & 3) * 8,
                           &Bs[0][0] + ((size_t)t * 256 + (tid & 192)) * 8);
            }
            __syncthreads();                    // drains vmcnt before ds_read
            f16x8 af[FM], bf[FN];
            #pragma unroll
            for (int i = 0; i < FM; ++i)
                af[i] = *(const f16x8*)&As[wrow * WM + i * 16 + lr][lq * 8];
            #pragma unroll
            for (int j = 0; j < FN; ++j)
                bf[j] = *(const f16x8*)&Bs[wcol * WN + j * 16 + lr][lq * 8];
            #pragma unroll
            for (int i = 0; i < FM; ++i)
                #pragma unroll
                for (int j = 0; j < FN; ++j)
                    acc[i][j] = __builtin_amdgcn_mfma_f32_16x16x32_f16(af[i], bf[j], acc[i][j], 0, 0, 0);
        }
    }

    if (FUSECELL) {
        // cols are permuted: col = 4*feat_local + gate (i,f,g,o). Per lane-quad,
        // a 3-shuffle 4x4 transpose yields all 4 gates of one (row,feat) per lane.
        const int q  = lane & 3;
        const int kk = (lane >> 2) & 3;
        #pragma unroll
        for (int i = 0; i < FM; ++i) {
            #pragma unroll
            for (int j = 0; j < FN; ++j) {
                const int col  = bn + wcol * WN + j * 16 + lr;
                const int row0 = bm + wrow * WM + i * 16 + lq * 4;
                float x[4];
                #pragma unroll
                for (int r = 0; r < 4; ++r)
                    x[r] = acc[i][j][r] + (float)pre[(size_t)(row0 + r) * G4 + col];
                float g4[4];
                #pragma unroll
                for (int k = 0; k < 4; ++k) {
                    int srcq = (q + k) & 3;
                    int src  = (lane & ~3) | srcq;
                    g4[srcq] = __shfl(x[(q - k + 4) & 3], src, 64);
                }
                const int row  = row0 + q;
                const int feat = ((bn + wcol * WN + j * 16) >> 2) + kk;
                const float i_ = sigm(g4[0]);
                const float f_ = sigm(g4[1]);
                const float g_ = tanhf(g4[2]);
                const float o_ = sigm(g4[3]);
                const size_t cid = ((size_t)(blockIdx.y * gridDim.x + blockIdx.x) * (FM * FN)
                                    + i * FN + j) * 256 + tid;
                float cold = first ? 0.f : cbuf[cid];
                float cn = i_ * g_ + f_ * cold;
                cbuf[cid] = cn;                 // f32 — f16 here injects 2.4e-4/iter
                float hn = o_ * tanhf(cn) + fin[(size_t)row * FEAT + feat];
                hh[(size_t)row * FEAT + feat] = (f16)hn;
                if (writeH) hout[(size_t)row * FEAT + feat] = hn;
            }
        }
    } else {
        // epilogue: C/D layout col=lane&15, row=(lane>>4)*4+reg (m89/m91-verified)
        #pragma unroll
        for (int i = 0; i < FM; ++i) {
            #pragma unroll
            for (int j = 0; j < FN; ++j) {
                const int col  = bn + wcol * WN + j * 16 + lr;
                const int row0 = bm + wrow * WM + i * 16 + lq * 4;
                float badd = HASBIAS ? bias[col] : 0.f;
                #pragma unroll
                for (int r = 0; r < 4; ++r) {
                    size_t off = (size_t)(row0 + r) * ldc + col;
                    float v = acc[i][j][r] + badd;
                    if (OUTF16) ((f16*)Cv)[off] = (f16)v;
                    else        ((float*)Cv)[off] = v;
                }
            }
        }
    }
}

// -------- softmax along contiguous rows; in f32 [rows][4096] -> out f16 --------
__global__ __launch_bounds__(256) void softmax_rows_kernel(
    const float* __restrict__ X, f16* __restrict__ Y)
{
    const int row = blockIdx.x;
    const float* x = X + (size_t)row * NB;
    f16* y = Y + (size_t)row * NB;
    const int tid = threadIdx.x;
    float v[16];
    float mx = -1e30f;
    #pragma unroll
    for (int i = 0; i < 16; ++i) { v[i] = x[tid + (i << 8)]; mx = fmaxf(mx, v[i]); }
    #pragma unroll
    for (int off = 32; off > 0; off >>= 1) mx = fmaxf(mx, __shfl_down(mx, off));
    __shared__ float sm[4];
    if ((tid & 63) == 0) sm[tid >> 6] = mx;
    __syncthreads();
    mx = fmaxf(fmaxf(sm[0], sm[1]), fmaxf(sm[2], sm[3]));
    float s = 0.f;
    #pragma unroll
    for (int i = 0; i < 16; ++i) { v[i] = __expf(v[i] - mx); s += v[i]; }
    #pragma unroll
    for (int off = 32; off > 0; off >>= 1) s += __shfl_down(s, off);
    __shared__ float ss[4];
    if ((tid & 63) == 0) ss[tid >> 6] = s;
    __syncthreads();
    s = ss[0] + ss[1] + ss[2] + ss[3];
    const float inv = 1.f / s;
    #pragma unroll
    for (int i = 0; i < 16; ++i) y[tid + (i << 8)] = (f16)(v[i] * inv);
}

// -------- transpose: f16 [R][C] -> f16 [C][R] --------
__global__ __launch_bounds__(256) void transpose_f16_kernel(
    const f16* __restrict__ in, f16* __restrict__ out, int R, int C)
{
    __shared__ f16 t[64][65];
    const int r0 = blockIdx.y * 64, c0 = blockIdx.x * 64;
    const int lr = threadIdx.x & 63, lw = threadIdx.x >> 6;
    #pragma unroll
    for (int i = 0; i < 16; ++i) {
        int rr = lw * 16 + i;
        t[rr][lr] = in[(size_t)(r0 + rr) * C + c0 + lr];
    }
    __syncthreads();
    #pragma unroll
    for (int i = 0; i < 16; ++i) {
        int cc = lw * 16 + i;
        out[(size_t)(c0 + cc) * R + r0 + lr] = t[lr][cc];
    }
}

// -------- f32 -> f16 convert --------
__global__ __launch_bounds__(256) void cvt_f16_kernel(
    const float* __restrict__ in, f16* __restrict__ out, int n)
{
    int idx = (blockIdx.x * 256 + threadIdx.x) * 4;
    if (idx < n) {
        float4 v = *(const float4*)(in + idx);
        f16x4 o = {(f16)v.x, (f16)v.y, (f16)v.z, (f16)v.w};
        *(f16x4*)(out + idx) = o;
    }
}

// -------- row-permuted f16 conversion: dst row 4*(j&1023)+(j>>10) = src row j ----
__global__ __launch_bounds__(256) void cvt_perm_kernel(
    const float* __restrict__ in, f16* __restrict__ out, int ld)
{
    int idx = (blockIdx.x * 256 + threadIdx.x) * 4;
    int j = idx / ld, k = idx % ld;
    int dst = 4 * (j & 1023) + (j >> 10);
    float4 v = *(const float4*)(in + idx);
    f16x4 o = {(f16)v.x, (f16)v.y, (f16)v.z, (f16)v.w};
    *(f16x4*)(out + (size_t)dst * ld + k) = o;
}

// -------- permuted combined bias: bias_p[4*(j&1023)+(j>>10)] = bih[j]+bhh[j] ----
__global__ __launch_bounds__(256) void bias_perm_kernel(
    const float* __restrict__ bih, const float* __restrict__ bhh, float* __restrict__ out)
{
    int j = blockIdx.x * 256 + threadIdx.x;
    out[4 * (j & 1023) + (j >> 10)] = bih[j] + bhh[j];
}

// -------- f32 -> (hi f16, lo f16) split --------
__global__ __launch_bounds__(256) void split_hilo_kernel(
    const float* __restrict__ in, f16* __restrict__ hi, f16* __restrict__ lo, int n)
{
    int idx = (blockIdx.x * 256 + threadIdx.x) * 4;
    if (idx < n) {
        float4 v = *(const float4*)(in + idx);
        f16x4 h = {(f16)v.x, (f16)v.y, (f16)v.z, (f16)v.w};
        f16x4 l = {(f16)(v.x - (float)h.x), (f16)(v.y - (float)h.y),
                   (f16)(v.z - (float)h.z), (f16)(v.w - (float)h.w)};
        *(f16x4*)(hi + idx) = h;
        *(f16x4*)(lo + idx) = l;
    }
}

extern "C" void kernel_launch(void* const* d_in, const int* in_sizes, int n_in,
                              void* d_out, int out_size, void* d_ws, size_t ws_size,
                              hipStream_t stream) {
    const float* f   = (const float*)d_in[0];   // [NB, FEAT]
    const float* G   = (const float*)d_in[1];   // [MSUP, FEAT]
    const float* Wih = (const float*)d_in[2];   // [G4, 2*FEAT]
    const float* Whh = (const float*)d_in[3];   // [G4, FEAT]
    const float* bih = (const float*)d_in[4];   // [G4]
    const float* bhh = (const float*)d_in[5];   // [G4]
    float* h = (float*)d_out;                   // [NB, FEAT]

    char* W = (char*)d_ws;
    f16*   pre_h   = (f16*)(W);                          // 32 MB [NB][G4] (permuted cols)
    float* aT      = (float*)(W + (size_t)(32 << 20));   //  8 MB [MSUP][NB]
    f16*   aTh     = (f16*)(W + (size_t)(40 << 20));     //  4 MB [MSUP][NB]
    f16*   a_h     = (f16*)(W + (size_t)(44 << 20));     //  4 MB [NB][MSUP]
    float* cbuf    = (float*)(W + (size_t)(48 << 20));   // 16 MB block-private c (f32!)
    f16*   h0      = (f16*)(W + (size_t)(64 << 20));     //  8 MB [NB][FEAT] = f16(f)
    f16*   hA      = (f16*)(W + (size_t)(72 << 20));     //  8 MB h ping
    f16*   hB      = (f16*)(W + (size_t)(80 << 20));     //  8 MB h pong
    f16*   Wih_h   = (f16*)(W + (size_t)(88 << 20));     // 16 MB [G4][2F] (permuted rows)
    f16*   Whh_h   = (f16*)(W + (size_t)(104 << 20));    //  8 MB [G4][F]  (permuted rows)
    float* Wr32    = (float*)(W + (size_t)(112 << 20));  //  8 MB [G4][MSUP] (permuted rows)
    f16*   Wr_hi   = (f16*)(W + (size_t)(120 << 20));    //  4 MB
    f16*   Wr_lo   = (f16*)(W + (size_t)(124 << 20));    //  4 MB
    f16*   G_h     = (f16*)(W + (size_t)(128 << 20));    //  1 MB [MSUP][FEAT]
    float* bias_p  = (float*)(W + (size_t)(129 << 20));  // 16 KB

    const f16* NF = nullptr;
    const dim3 blk(256);

    // setup (every call — ws is re-poisoned)
    cvt_f16_kernel<<<(NB * FEAT) / 1024, blk, 0, stream>>>(f, h0, NB * FEAT);
    cvt_perm_kernel<<<(G4 * 2 * FEAT) / 1024, blk, 0, stream>>>(Wih, Wih_h, 2 * FEAT);
    cvt_perm_kernel<<<(G4 * FEAT) / 1024, blk, 0, stream>>>(Whh, Whh_h, FEAT);
    cvt_f16_kernel<<<(MSUP * FEAT) / 1024, blk, 0, stream>>>(G, G_h, MSUP * FEAT);
    bias_perm_kernel<<<G4 / 256, blk, 0, stream>>>(bih, bhh, bias_p);

    // pre = f @ W_f^T + biases (permuted cols; constant across iterations)
    mfma_nt<128, 128, 2, 2, true, true, false><<<dim3(G4 / 128, NB / 128), blk, 0, stream>>>(
        pre_h, G4,
        h0, FEAT, Wih_h, 2 * FEAT, FEAT,
        NF, 0, NF, 0, 0, NF, 0, NF, 0, 0,
        bias_p, NF, nullptr, nullptr, nullptr, nullptr, 0, 0);

    // Wr' = W_r @ G^T in f32 (permuted rows), then hi/lo f16 split (R5/R6 lesson).
    mfma_nt<128, 128, 2, 2, false, false, false><<<dim3(MSUP / 128, G4 / 128), blk, 0, stream>>>(
        Wr32, MSUP,
        Wih_h + FEAT, 2 * FEAT, G_h, FEAT, FEAT,
        NF, 0, NF, 0, 0, NF, 0, NF, 0, 0,
        nullptr, NF, nullptr, nullptr, nullptr, nullptr, 0, 0);
    split_hilo_kernel<<<(G4 * MSUP) / 1024, blk, 0, stream>>>(Wr32, Wr_hi, Wr_lo, G4 * MSUP);

    const f16* hcur = h0;
    for (int it = 0; it < NWAYS; ++it) {
        // aT[m][n] = G[m]·h[n] (transposed → contiguous row softmax)
        mfma_nt<64, 64, 2, 2, false, false, false><<<dim3(NB / 64, MSUP / 64), blk, 0, stream>>>(
            aT, NB,
            G_h, FEAT, hcur, FEAT, FEAT,
            NF, 0, NF, 0, 0, NF, 0, NF, 0, 0,
            nullptr, NF, nullptr, nullptr, nullptr, nullptr, 0, 0);

        softmax_rows_kernel<<<MSUP, blk, 0, stream>>>(aT, aTh);
        transpose_f16_kernel<<<dim3(NB / 64, MSUP / 64), blk, 0, stream>>>(aTh, a_h, MSUP, NB);

        // gates = pre + a@Wr_hi^T + a@Wr_lo^T + h@Whh^T, fused LSTM cell epilogue
        f16* hnext = (it & 1) ? hB : hA;
        mfma_nt<128, 128, 2, 2, false, false, true><<<dim3(G4 / 128, NB / 128), blk, 0, stream>>>(
            nullptr, G4,
            a_h, MSUP, Wr_hi, MSUP, MSUP,
            a_h, MSUP, Wr_lo, MSUP, MSUP,
            hcur, FEAT, Whh_h, FEAT, FEAT,
            nullptr, pre_h, f, cbuf, hnext, h, it == 0, it == NWAYS - 1);
        hcur = hnext;
    }
}

// Round 9
// 2853.232 us; speedup vs baseline: 1.0746x; 1.0746x over previous
//
#include <hip/hip_runtime.h>
#include <math.h>

#define NB    4096   // batch N
#define FEAT  1024
#define MSUP  512    // SUPPORT
#define G4    4096   // 4*FEAT
#define NWAYS 20     // n_ways fixed to 20 per setup_inputs()

typedef _Float16 f16;
typedef f16 f16x8 __attribute__((ext_vector_type(8)));
typedef f16 f16x4 __attribute__((ext_vector_type(4)));
typedef float f32x4 __attribute__((ext_vector_type(4)));
typedef unsigned int u32;
#define GLOBAL_AS __attribute__((address_space(1)))
#define LDS_AS    __attribute__((address_space(3)))

__device__ __forceinline__ void load_lds16(const void* g, void* l) {
    __builtin_amdgcn_global_load_lds((const GLOBAL_AS u32*)g, (LDS_AS u32*)l, 16, 0, 0);
}

__device__ __forceinline__ float sigm(float x) { return 1.f / (1.f + __expf(-x)); }

// ---------------- plain f16 MFMA NT GEMM (R2-proven core) ----------------
// C[m,n] = sum_k A[m,k]*B[n,k]; up to three (A,B,K) pairs; optional bias.
template<int BM, int BN, int WROWS, int WCOLS, bool OUTF16, bool HASBIAS>
__global__ __launch_bounds__(256) void mfma_nt(
    void* __restrict__ Cv, int ldc,
    const f16* __restrict__ A1, int lda1, const f16* __restrict__ B1, int ldb1, int K1,
    const f16* __restrict__ A2, int lda2, const f16* __restrict__ B2, int ldb2, int K2,
    const f16* __restrict__ A3, int lda3, const f16* __restrict__ B3, int ldb3, int K3,
    const float* __restrict__ bias)
{
    constexpr int BK = 32;
    constexpr int WM = BM / WROWS, WN = BN / WCOLS;
    constexpr int FM = WM / 16,   FN = WN / 16;
    __shared__ f16 As[BM][BK];
    __shared__ f16 Bs[BN][BK];
    const int tid  = threadIdx.x;
    const int lane = tid & 63;
    const int wrow = (tid >> 6) % WROWS, wcol = (tid >> 6) / WROWS;
    const int bm = blockIdx.y * BM, bn = blockIdx.x * BN;
    const int lr = lane & 15, lq = lane >> 4;

    f32x4 acc[FM][FN] = {};

    #pragma unroll
    for (int pass = 0; pass < 3; ++pass) {
        const f16* A = pass == 0 ? A1 : (pass == 1 ? A2 : A3);
        const f16* B = pass == 0 ? B1 : (pass == 1 ? B2 : B3);
        const int lda = pass == 0 ? lda1 : (pass == 1 ? lda2 : lda3);
        const int ldb = pass == 0 ? ldb1 : (pass == 1 ? ldb2 : ldb3);
        const int K   = pass == 0 ? K1  : (pass == 1 ? K2  : K3);
        if (!A) break;
        #pragma unroll 1
        for (int k0 = 0; k0 < K; k0 += BK) {
            __syncthreads();
            #pragma unroll
            for (int t = 0; t < (BM * 4) / 256; ++t) {
                int c = t * 256 + tid;
                load_lds16(A + (size_t)(bm + (c >> 2)) * lda + k0 + (c & 3) * 8,
                           &As[0][0] + ((size_t)t * 256 + (tid & 192)) * 8);
            }
            #pragma unroll
            for (int t = 0; t < (BN * 4) / 256; ++t) {
                int c = t * 256 + tid;
                load_lds16(B + (size_t)(bn + (c >> 2)) * ldb + k0 + (c & 3) * 8,
                           &Bs[0][0] + ((size_t)t * 256 + (tid & 192)) * 8);
            }
            __syncthreads();
            f16x8 af[FM], bf[FN];
            #pragma unroll
            for (int i = 0; i < FM; ++i)
                af[i] = *(const f16x8*)&As[wrow * WM + i * 16 + lr][lq * 8];
            #pragma unroll
            for (int j = 0; j < FN; ++j)
                bf[j] = *(const f16x8*)&Bs[wcol * WN + j * 16 + lr][lq * 8];
            #pragma unroll
            for (int i = 0; i < FM; ++i)
                #pragma unroll
                for (int j = 0; j < FN; ++j)
                    acc[i][j] = __builtin_amdgcn_mfma_f32_16x16x32_f16(af[i], bf[j], acc[i][j], 0, 0, 0);
        }
    }

    #pragma unroll
    for (int i = 0; i < FM; ++i) {
        #pragma unroll
        for (int j = 0; j < FN; ++j) {
            const int col  = bn + wcol * WN + j * 16 + lr;
            const int row0 = bm + wrow * WM + i * 16 + lq * 4;
            float badd = HASBIAS ? bias[col] : 0.f;
            #pragma unroll
            for (int r = 0; r < 4; ++r) {
                size_t off = (size_t)(row0 + r) * ldc + col;
                float v = acc[i][j][r] + badd;
                if (OUTF16) ((f16*)Cv)[off] = (f16)v;
                else        ((float*)Cv)[off] = v;
            }
        }
    }
}

// ------------- fused gates GEMM + LSTM cell (gate-interleaved cols) -------------
// gates = pre + a@WrHi^T + a@WrLo^T + h@Whh^T; cell in epilogue.
// Pass 1 (K=512): a staged ONCE with BOTH WrHi/WrLo tiles (paired-B).
// Pass 2 (K=1024): h @ Whh.
// R7 lesson: c stays f32; cell math matches R8-passing path exactly.
__global__ __launch_bounds__(256) void gates_fused(
    const f16* __restrict__ a,     // [NB][MSUP]
    const f16* __restrict__ WrHi,  // [G4][MSUP] (permuted rows)
    const f16* __restrict__ WrLo,  // [G4][MSUP]
    const f16* __restrict__ h,     // [NB][FEAT]
    const f16* __restrict__ Whh,   // [G4][FEAT] (permuted rows)
    const f16* __restrict__ pre,   // [NB][G4] (permuted cols)
    const float* __restrict__ fin, // [NB][FEAT] f32
    float* __restrict__ cbuf,      // block-private c, f32
    f16* __restrict__ hh,          // [NB][FEAT] f16 h_next
    float* __restrict__ hout,      // [NB][FEAT] f32 (writeH)
    int first, int writeH)
{
    constexpr int BM = 128, BN = 128, BK = 32;
    constexpr int WM = 64, WN = 64, FM = 4, FN = 4;
    __shared__ f16 As[BM][BK];
    __shared__ f16 BsH[BN][BK];
    __shared__ f16 BsL[BN][BK];
    const int tid  = threadIdx.x;
    const int lane = tid & 63;
    const int wrow = (tid >> 6) & 1, wcol = (tid >> 6) >> 1;
    const int bm = blockIdx.y * BM, bn = blockIdx.x * BN;
    const int lr = lane & 15, lq = lane >> 4;

    f32x4 acc[FM][FN] = {};

    // ---- pass 1: K=512 over a with paired Wr hi/lo B-tiles ----
    #pragma unroll 1
    for (int k0 = 0; k0 < MSUP; k0 += BK) {
        __syncthreads();
        #pragma unroll
        for (int t = 0; t < 2; ++t) {
            int c = t * 256 + tid;
            load_lds16(a + (size_t)(bm + (c >> 2)) * MSUP + k0 + (c & 3) * 8,
                       &As[0][0] + ((size_t)t * 256 + (tid & 192)) * 8);
        }
        #pragma unroll
        for (int t = 0; t < 2; ++t) {
            int c = t * 256 + tid;
            load_lds16(WrHi + (size_t)(bn + (c >> 2)) * MSUP + k0 + (c & 3) * 8,
                       &BsH[0][0] + ((size_t)t * 256 + (tid & 192)) * 8);
        }
        #pragma unroll
        for (int t = 0; t < 2; ++t) {
            int c = t * 256 + tid;
            load_lds16(WrLo + (size_t)(bn + (c >> 2)) * MSUP + k0 + (c & 3) * 8,
                       &BsL[0][0] + ((size_t)t * 256 + (tid & 192)) * 8);
        }
        __syncthreads();
        f16x8 af[FM], bh[FN], bl[FN];
        #pragma unroll
        for (int i = 0; i < FM; ++i)
            af[i] = *(const f16x8*)&As[wrow * WM + i * 16 + lr][lq * 8];
        #pragma unroll
        for (int j = 0; j < FN; ++j) {
            bh[j] = *(const f16x8*)&BsH[wcol * WN + j * 16 + lr][lq * 8];
            bl[j] = *(const f16x8*)&BsL[wcol * WN + j * 16 + lr][lq * 8];
        }
        #pragma unroll
        for (int i = 0; i < FM; ++i)
            #pragma unroll
            for (int j = 0; j < FN; ++j) {
                acc[i][j] = __builtin_amdgcn_mfma_f32_16x16x32_f16(af[i], bh[j], acc[i][j], 0, 0, 0);
                acc[i][j] = __builtin_amdgcn_mfma_f32_16x16x32_f16(af[i], bl[j], acc[i][j], 0, 0, 0);
            }
    }

    // ---- pass 2: K=1024 over h with Whh ----
    #pragma unroll 1
    for (int k0 = 0; k0 < FEAT; k0 += BK) {
        __syncthreads();
        #pragma unroll
        for (int t = 0; t < 2; ++t) {
            int c = t * 256 + tid;
            load_lds16(h + (size_t)(bm + (c >> 2)) * FEAT + k0 + (c & 3) * 8,
                       &As[0][0] + ((size_t)t * 256 + (tid & 192)) * 8);
        }
        #pragma unroll
        for (int t = 0; t < 2; ++t) {
            int c = t * 256 + tid;
            load_lds16(Whh + (size_t)(bn + (c >> 2)) * FEAT + k0 + (c & 3) * 8,
                       &BsH[0][0] + ((size_t)t * 256 + (tid & 192)) * 8);
        }
        __syncthreads();
        f16x8 af[FM], bf[FN];
        #pragma unroll
        for (int i = 0; i < FM; ++i)
            af[i] = *(const f16x8*)&As[wrow * WM + i * 16 + lr][lq * 8];
        #pragma unroll
        for (int j = 0; j < FN; ++j)
            bf[j] = *(const f16x8*)&BsH[wcol * WN + j * 16 + lr][lq * 8];
        #pragma unroll
        for (int i = 0; i < FM; ++i)
            #pragma unroll
            for (int j = 0; j < FN; ++j)
                acc[i][j] = __builtin_amdgcn_mfma_f32_16x16x32_f16(af[i], bf[j], acc[i][j], 0, 0, 0);
    }

    // ---- fused cell epilogue ----
    // cols permuted: col = 4*feat_local + gate. Quad transpose (3-shuffle) gives
    // each lane all 4 gate accs of one (row,feat); pre added POST-shuffle as one
    // f16x4 (gates of a feature are contiguous) — bit-identical to pre-shuffle add.
    const int q  = lane & 3;
    const int kk = (lane >> 2) & 3;
    #pragma unroll
    for (int i = 0; i < FM; ++i) {
        #pragma unroll
        for (int j = 0; j < FN; ++j) {
            const int cb   = bn + wcol * WN + j * 16;       // frag col base (mult of 16)
            const int row0 = bm + wrow * WM + i * 16 + lq * 4;
            float x[4];
            #pragma unroll
            for (int r = 0; r < 4; ++r) x[r] = acc[i][j][r];
            float g4[4];
            #pragma unroll
            for (int k = 0; k < 4; ++k) {
                int srcq = (q + k) & 3;
                int src  = (lane & ~3) | srcq;
                g4[srcq] = __shfl(x[(q - k + 4) & 3], src, 64);
            }
            const int row  = row0 + q;
            const int feat = (cb >> 2) + kk;
            f16x4 p = *(const f16x4*)(pre + (size_t)row * G4 + cb + 4 * kk);
            const float i_ = sigm(g4[0] + (float)p[0]);
            const float f_ = sigm(g4[1] + (float)p[1]);
            const float g_ = tanhf(g4[2] + (float)p[2]);
            const float o_ = sigm(g4[3] + (float)p[3]);
            const size_t cid = ((size_t)(blockIdx.y * gridDim.x + blockIdx.x) * (FM * FN)
                                + i * FN + j) * 256 + tid;
            float cold = first ? 0.f : cbuf[cid];
            float cn = i_ * g_ + f_ * cold;
            cbuf[cid] = cn;                 // f32 — f16 here injects 2.4e-4/iter (R7 fail)
            float hn = o_ * tanhf(cn) + fin[(size_t)row * FEAT + feat];
            hh[(size_t)row * FEAT + feat] = (f16)hn;
            if (writeH) hout[(size_t)row * FEAT + feat] = hn;
        }
    }
}

// -------- softmax along contiguous rows; in f32 [rows][4096] -> out f16 --------
__global__ __launch_bounds__(256) void softmax_rows_kernel(
    const float* __restrict__ X, f16* __restrict__ Y)
{
    const int row = blockIdx.x;
    const float* x = X + (size_t)row * NB;
    f16* y = Y + (size_t)row * NB;
    const int tid = threadIdx.x;
    float v[16];
    float mx = -1e30f;
    #pragma unroll
    for (int i = 0; i < 16; ++i) { v[i] = x[tid + (i << 8)]; mx = fmaxf(mx, v[i]); }
    #pragma unroll
    for (int off = 32; off > 0; off >>= 1) mx = fmaxf(mx, __shfl_down(mx, off));
    __shared__ float sm[4];
    if ((tid & 63) == 0) sm[tid >> 6] = mx;
    __syncthreads();
    mx = fmaxf(fmaxf(sm[0], sm[1]), fmaxf(sm[2], sm[3]));
    float s = 0.f;
    #pragma unroll
    for (int i = 0; i < 16; ++i) { v[i] = __expf(v[i] - mx); s += v[i]; }
    #pragma unroll
    for (int off = 32; off > 0; off >>= 1) s += __shfl_down(s, off);
    __shared__ float ss[4];
    if ((tid & 63) == 0) ss[tid >> 6] = s;
    __syncthreads();
    s = ss[0] + ss[1] + ss[2] + ss[3];
    const float inv = 1.f / s;
    #pragma unroll
    for (int i = 0; i < 16; ++i) y[tid + (i << 8)] = (f16)(v[i] * inv);
}

// -------- transpose: f16 [R][C] -> f16 [C][R] --------
__global__ __launch_bounds__(256) void transpose_f16_kernel(
    const f16* __restrict__ in, f16* __restrict__ out, int R, int C)
{
    __shared__ f16 t[64][65];
    const int r0 = blockIdx.y * 64, c0 = blockIdx.x * 64;
    const int lr = threadIdx.x & 63, lw = threadIdx.x >> 6;
    #pragma unroll
    for (int i = 0; i < 16; ++i) {
        int rr = lw * 16 + i;
        t[rr][lr] = in[(size_t)(r0 + rr) * C + c0 + lr];
    }
    __syncthreads();
    #pragma unroll
    for (int i = 0; i < 16; ++i) {
        int cc = lw * 16 + i;
        out[(size_t)(c0 + cc) * R + r0 + lr] = t[lr][cc];
    }
}

// -------- f32 -> f16 convert --------
__global__ __launch_bounds__(256) void cvt_f16_kernel(
    const float* __restrict__ in, f16* __restrict__ out, int n)
{
    int idx = (blockIdx.x * 256 + threadIdx.x) * 4;
    if (idx < n) {
        float4 v = *(const float4*)(in + idx);
        f16x4 o = {(f16)v.x, (f16)v.y, (f16)v.z, (f16)v.w};
        *(f16x4*)(out + idx) = o;
    }
}

// -------- row-permuted f16 conversion: dst row 4*(j&1023)+(j>>10) = src row j ----
__global__ __launch_bounds__(256) void cvt_perm_kernel(
    const float* __restrict__ in, f16* __restrict__ out, int ld)
{
    int idx = (blockIdx.x * 256 + threadIdx.x) * 4;
    int j = idx / ld, k = idx % ld;
    int dst = 4 * (j & 1023) + (j >> 10);
    float4 v = *(const float4*)(in + idx);
    f16x4 o = {(f16)v.x, (f16)v.y, (f16)v.z, (f16)v.w};
    *(f16x4*)(out + (size_t)dst * ld + k) = o;
}

// -------- permuted combined bias: bias_p[4*(j&1023)+(j>>10)] = bih[j]+bhh[j] ----
__global__ __launch_bounds__(256) void bias_perm_kernel(
    const float* __restrict__ bih, const float* __restrict__ bhh, float* __restrict__ out)
{
    int j = blockIdx.x * 256 + threadIdx.x;
    out[4 * (j & 1023) + (j >> 10)] = bih[j] + bhh[j];
}

// -------- f32 -> (hi f16, lo f16) split --------
__global__ __launch_bounds__(256) void split_hilo_kernel(
    const float* __restrict__ in, f16* __restrict__ hi, f16* __restrict__ lo, int n)
{
    int idx = (blockIdx.x * 256 + threadIdx.x) * 4;
    if (idx < n) {
        float4 v = *(const float4*)(in + idx);
        f16x4 h = {(f16)v.x, (f16)v.y, (f16)v.z, (f16)v.w};
        f16x4 l = {(f16)(v.x - (float)h.x), (f16)(v.y - (float)h.y),
                   (f16)(v.z - (float)h.z), (f16)(v.w - (float)h.w)};
        *(f16x4*)(hi + idx) = h;
        *(f16x4*)(lo + idx) = l;
    }
}

extern "C" void kernel_launch(void* const* d_in, const int* in_sizes, int n_in,
                              void* d_out, int out_size, void* d_ws, size_t ws_size,
                              hipStream_t stream) {
    const float* f   = (const float*)d_in[0];   // [NB, FEAT]
    const float* G   = (const float*)d_in[1];   // [MSUP, FEAT]
    const float* Wih = (const float*)d_in[2];   // [G4, 2*FEAT]
    const float* Whh = (const float*)d_in[3];   // [G4, FEAT]
    const float* bih = (const float*)d_in[4];   // [G4]
    const float* bhh = (const float*)d_in[5];   // [G4]
    float* h = (float*)d_out;                   // [NB, FEAT]

    char* W = (char*)d_ws;
    f16*   pre_h   = (f16*)(W);                          // 32 MB [NB][G4] (permuted cols)
    float* aT      = (float*)(W + (size_t)(32 << 20));   //  8 MB [MSUP][NB]
    f16*   aTh     = (f16*)(W + (size_t)(40 << 20));     //  4 MB [MSUP][NB]
    f16*   a_h     = (f16*)(W + (size_t)(44 << 20));     //  4 MB [NB][MSUP]
    float* cbuf    = (float*)(W + (size_t)(48 << 20));   // 16 MB block-private c (f32!)
    f16*   h0      = (f16*)(W + (size_t)(64 << 20));     //  8 MB [NB][FEAT] = f16(f)
    f16*   hA      = (f16*)(W + (size_t)(72 << 20));     //  8 MB h ping
    f16*   hB      = (f16*)(W + (size_t)(80 << 20));     //  8 MB h pong
    f16*   Wih_h   = (f16*)(W + (size_t)(88 << 20));     // 16 MB [G4][2F] (permuted rows)
    f16*   Whh_h   = (f16*)(W + (size_t)(104 << 20));    //  8 MB [G4][F]  (permuted rows)
    float* Wr32    = (float*)(W + (size_t)(112 << 20));  //  8 MB [G4][MSUP] (permuted rows)
    f16*   Wr_hi   = (f16*)(W + (size_t)(120 << 20));    //  4 MB
    f16*   Wr_lo   = (f16*)(W + (size_t)(124 << 20));    //  4 MB
    f16*   G_h     = (f16*)(W + (size_t)(128 << 20));    //  1 MB [MSUP][FEAT]
    float* bias_p  = (float*)(W + (size_t)(129 << 20));  // 16 KB

    const f16* NF = nullptr;
    const dim3 blk(256);

    // setup (every call — ws is re-poisoned)
    cvt_f16_kernel<<<(NB * FEAT) / 1024, blk, 0, stream>>>(f, h0, NB * FEAT);
    cvt_perm_kernel<<<(G4 * 2 * FEAT) / 1024, blk, 0, stream>>>(Wih, Wih_h, 2 * FEAT);
    cvt_perm_kernel<<<(G4 * FEAT) / 1024, blk, 0, stream>>>(Whh, Whh_h, FEAT);
    cvt_f16_kernel<<<(MSUP * FEAT) / 1024, blk, 0, stream>>>(G, G_h, MSUP * FEAT);
    bias_perm_kernel<<<G4 / 256, blk, 0, stream>>>(bih, bhh, bias_p);

    // pre = f @ W_f^T + biases (permuted cols; constant across iterations)
    mfma_nt<128, 128, 2, 2, true, true><<<dim3(G4 / 128, NB / 128), blk, 0, stream>>>(
        pre_h, G4,
        h0, FEAT, Wih_h, 2 * FEAT, FEAT,
        NF, 0, NF, 0, 0, NF, 0, NF, 0, 0,
        bias_p);

    // Wr' = W_r @ G^T in f32 (permuted rows), then hi/lo f16 split (R5/R6 lesson).
    mfma_nt<128, 128, 2, 2, false, false><<<dim3(MSUP / 128, G4 / 128), blk, 0, stream>>>(
        Wr32, MSUP,
        Wih_h + FEAT, 2 * FEAT, G_h, FEAT, FEAT,
        NF, 0, NF, 0, 0, NF, 0, NF, 0, 0,
        nullptr);
    split_hilo_kernel<<<(G4 * MSUP) / 1024, blk, 0, stream>>>(Wr32, Wr_hi, Wr_lo, G4 * MSUP);

    const f16* hcur = h0;
    for (int it = 0; it < NWAYS; ++it) {
        // aT[m][n] = G[m]·h[n] (transposed → contiguous row softmax)
        mfma_nt<64, 64, 2, 2, false, false><<<dim3(NB / 64, MSUP / 64), blk, 0, stream>>>(
            aT, NB,
            G_h, FEAT, hcur, FEAT, FEAT,
            NF, 0, NF, 0, 0, NF, 0, NF, 0, 0,
            nullptr);

        softmax_rows_kernel<<<MSUP, blk, 0, stream>>>(aT, aTh);
        transpose_f16_kernel<<<dim3(NB / 64, MSUP / 64), blk, 0, stream>>>(aTh, a_h, MSUP, NB);

        // gates = pre + a@Wr_hi^T + a@Wr_lo^T + h@Whh^T, fused LSTM cell epilogue
        f16* hnext = (it & 1) ? hB : hA;
        gates_fused<<<dim3(G4 / 128, NB / 128), blk, 0, stream>>>(
            a_h, Wr_hi, Wr_lo, hcur, Whh_h,
            pre_h, f, cbuf, hnext, h, it == 0, it == NWAYS - 1);
        hcur = hnext;
    }
}